// Round 1
// baseline (5101.937 us; speedup 1.0000x reference)
//
#include <hip/hip_runtime.h>

#define VOCAB   4096
#define HIDDEN  512
#define BATCH   64
#define TSTEPS  512
#define NWG     8        // workgroups in the RNN scan (64 hidden cols each)
#define NARRIVE (NWG*4)  // per-WAVE arrivals: 8 WGs x 4 waves

typedef short bf16x8 __attribute__((ext_vector_type(8)));   // 8 bf16 = 4 VGPRs
typedef float f32x4  __attribute__((ext_vector_type(4)));

// fp32 -> bf16 round-to-nearest-even (values are finite; no NaN path needed)
__device__ __forceinline__ unsigned short f2bf(float f) {
  unsigned int x = __float_as_uint(f);
  unsigned int r = (x + 0x7fffu + ((x >> 16) & 1u)) >> 16;
  return (unsigned short)r;
}

// tanh via hw exp + rcp: tanh(x) = 1 - 2/(exp(2x)+1). Handles +-inf limits
// (rcp(inf)=0 -> +-1). Rel err ~1e-6 -- far below bf16 rounding already in
// the tolerance budget. ~5 VALU ops vs ~40 for libm tanhf.
__device__ __forceinline__ float tanh_fast(float x) {
  float e = __expf(2.0f * x);                       // v_mul + v_exp_f32
  return fmaf(-2.0f, __builtin_amdgcn_rcpf(e + 1.0f), 1.0f);
}

// async global->LDS, 16B per lane (used by logits_gemm only).
__device__ __forceinline__ void async16(const void* g, void* l) {
  __builtin_amdgcn_global_load_lds(
      (const __attribute__((address_space(1))) unsigned int*)g,
      (__attribute__((address_space(3))) unsigned int*)l, 16, 0, 0);
}

// ---------------------------------------------------------------------------
// prep_small: convert initial hidden (fp32) to bf16 hbuf[0] and zero the 512
// per-step barrier counters (ws is poisoned 0xAA each launch).
// grid 128 x 256 = 32768 threads exactly.
__global__ void prep_small(const float* __restrict__ hidden,
                           unsigned short* __restrict__ hbuf,
                           int* __restrict__ bar) {
  int i = blockIdx.x * 256 + threadIdx.x;
  hbuf[i] = f2bf(hidden[i]);
  if (i < TSTEPS) bar[i] = 0;
}

// ---------------------------------------------------------------------------
// build_Wb: Wb[v][h] = W_ih[h][v] + b_ih[h] + b_hh[h]   (fp32, 4096x512)
// 64x64 LDS tile transpose. grid 512 (64 v-tiles x 8 h-tiles), block 256.
__global__ void build_Wb(const float* __restrict__ W_ih,
                         const float* __restrict__ b_ih,
                         const float* __restrict__ b_hh,
                         float* __restrict__ Wb) {
  __shared__ float t[64][65];
  int bx = blockIdx.x;
  int vt = bx & 63, ht = bx >> 6;
  int v0 = vt * 64, h0 = ht * 64;
  int tx = threadIdx.x & 15, ty = threadIdx.x >> 4;
#pragma unroll
  for (int a = 0; a < 4; ++a) {
    int h = h0 + ty + 16 * a;
    float4 v = *(const float4*)&W_ih[(size_t)h * VOCAB + v0 + tx * 4];
    t[ty + 16 * a][tx * 4 + 0] = v.x;
    t[ty + 16 * a][tx * 4 + 1] = v.y;
    t[ty + 16 * a][tx * 4 + 2] = v.z;
    t[ty + 16 * a][tx * 4 + 3] = v.w;
  }
  __syncthreads();
#pragma unroll
  for (int a = 0; a < 4; ++a) {
    int v = v0 + ty + 16 * a;
    int hh = h0 + tx * 4;
    float4 o;
    o.x = t[tx * 4 + 0][ty + 16 * a] + b_ih[hh + 0] + b_hh[hh + 0];
    o.y = t[tx * 4 + 1][ty + 16 * a] + b_ih[hh + 1] + b_hh[hh + 1];
    o.z = t[tx * 4 + 2][ty + 16 * a] + b_ih[hh + 2] + b_hh[hh + 2];
    o.w = t[tx * 4 + 3][ty + 16 * a] + b_ih[hh + 3] + b_hh[hh + 3];
    *(float4*)&Wb[(size_t)v * HIDDEN + hh] = o;
  }
}

// ---------------------------------------------------------------------------
// conv_wfc: W_fc fp32 -> bf16. 2097152 elems, 4/thread, grid 2048 x 256 exact.
__global__ void conv_wfc(const float* __restrict__ W, unsigned short* __restrict__ o) {
  int i = (blockIdx.x * 256 + threadIdx.x) * 4;
  float4 v = *(const float4*)&W[i];
  ushort4 u;
  u.x = f2bf(v.x); u.y = f2bf(v.y); u.z = f2bf(v.z); u.w = f2bf(v.w);
  *(ushort4*)&o[i] = u;
}

// ---------------------------------------------------------------------------
// rnn_scan v2: 8 WGs x 256 threads, WG owns hidden cols [64w, 64w+64).
// The whole W_hh slice lives in registers as MFMA *A*-fragments (256 VGPRs/lane
// at 1 wave/SIMD). No LDS. Cross-XCD h exchange entirely via relaxed agent-
// scope atomics (sc1 cache-bypass: stores/loads go straight to the coherence
// point), so the hot loop contains ZERO buffer_inv / buffer_wbl2 -- L2 stays
// warm for Wb and inp. Operand-swapped MFMA (A=W, B=h) puts each thread's 4
// accumulators on 4 consecutive hidden cols of one batch row: x-gather is one
// float4, h-store one aligned u64.
//
// Per-step protocol (per wave, no __syncthreads anywhere):
//   relaxed-spin bar[t-1]==32  ->  issue x float4 loads (idx prefetched at
//   t-1)  ->  issue 32 relaxed u64 h loads  ->  prefetch idx for t+1  ->
//   64 MFMAs  ->  tanh+pack  ->  4 relaxed u64 h stores  ->
//   s_waitcnt vmcnt(0)  ->  lane0: relaxed fetch_add(bar[t])  ->
//   outH/hlast stores (off the critical path).
__global__ __launch_bounds__(256) void rnn_scan(
    const float* __restrict__ Whh,      // [512][512] fp32
    const float* __restrict__ Wb,       // [4096][512] fp32 (biases folded)
    const int* __restrict__ inp,        // [64][512]
    unsigned short* __restrict__ hbuf,  // [2][64][512] bf16
    unsigned short* __restrict__ outH,  // [32768][512] bf16  (row = b*T + t)
    float* __restrict__ hlast,          // [64][512] fp32 (d_out tail)
    int* __restrict__ bar) {            // [512] arrival counters (pre-zeroed)
  const int tid  = threadIdx.x;
  const int wave = tid >> 6, lane = tid & 63;
  const int quad = lane >> 4, lrow = lane & 15;
  const int n0   = blockIdx.x * 64;     // WG's first hidden col
  const int b    = wave * 16 + lrow;    // this thread's batch row (B-frag col)

  // A-frags: lane holds Whh[n0 + nt*16 + lrow][kc*32 + quad*8 + j], j=0..7.
  // (identical per-lane pattern to a B-frag; operand roles swapped vs v1)
  bf16x8 wfrag[4][16];
#pragma unroll
  for (int nt = 0; nt < 4; ++nt) {
    const float* wsrc = Whh + (size_t)(n0 + nt * 16 + lrow) * HIDDEN + quad * 8;
#pragma unroll
    for (int kc = 0; kc < 16; ++kc) {
      float4 f0 = *(const float4*)(wsrc + kc * 32);
      float4 f1 = *(const float4*)(wsrc + kc * 32 + 4);
      bf16x8 v;
      v[0] = (short)f2bf(f0.x); v[1] = (short)f2bf(f0.y);
      v[2] = (short)f2bf(f0.z); v[3] = (short)f2bf(f0.w);
      v[4] = (short)f2bf(f1.x); v[5] = (short)f2bf(f1.y);
      v[6] = (short)f2bf(f1.z); v[7] = (short)f2bf(f1.w);
      wfrag[nt][kc] = v;
    }
  }

  int idx = inp[b * TSTEPS];            // x index for t=0 (prefetched)

  for (int t = 0; t < TSTEPS; ++t) {
    if (t > 0) {
      // Relaxed poll: sc1 load straight from the coherence point -- no
      // buffer_inv per iteration. Bounded: fail loud (wrong data), not hang.
      int lim = 1 << 16;
      while (__hip_atomic_load(&bar[t - 1], __ATOMIC_RELAXED,
                               __HIP_MEMORY_SCOPE_AGENT) < NARRIVE && --lim) {}
    }

    // x for THIS step: one float4 per n-subtile (idx already in a register,
    // so these issue immediately and hide under the h-load + MFMA phase).
    float4 xv[4];
#pragma unroll
    for (int nt = 0; nt < 4; ++nt)
      xv[nt] = *(const float4*)&Wb[(size_t)idx * HIDDEN + n0 + nt * 16 + quad * 4];

    // B-frags: h[b][kc*32 + quad*8 .. +8] via relaxed agent u64 loads (sc1:
    // read LLC where producers' sc1 stores landed; never fills/stales L2).
    const unsigned short* hsrc = hbuf + (size_t)(t & 1) * (BATCH * HIDDEN);
    const unsigned long long* hp =
        (const unsigned long long*)(hsrc + (size_t)b * HIDDEN + quad * 8);
    unsigned long long hl[16][2];
#pragma unroll
    for (int kc = 0; kc < 16; ++kc) {
      hl[kc][0] = __hip_atomic_load(hp + kc * 8, __ATOMIC_RELAXED,
                                    __HIP_MEMORY_SCOPE_AGENT);
      hl[kc][1] = __hip_atomic_load(hp + kc * 8 + 1, __ATOMIC_RELAXED,
                                    __HIP_MEMORY_SCOPE_AGENT);
    }

    // prefetch next step's x index (dependent Wb gather then issues at the
    // very top of step t+1, fully hidden)
    if (t + 1 < TSTEPS) idx = inp[b * TSTEPS + t + 1];

    f32x4 acc[4];
#pragma unroll
    for (int nt = 0; nt < 4; ++nt) acc[nt] = (f32x4){0.f, 0.f, 0.f, 0.f};
#pragma unroll
    for (int kc = 0; kc < 16; ++kc) {
      union { unsigned long long u[2]; bf16x8 v; } hu;
      hu.u[0] = hl[kc][0]; hu.u[1] = hl[kc][1];
#pragma unroll
      for (int nt = 0; nt < 4; ++nt)
        acc[nt] = __builtin_amdgcn_mfma_f32_16x16x32_bf16(
            wfrag[nt][kc], hu.v, acc[nt], 0, 0, 0);
    }

    // Epilogue. D layout: row(=n within tile)=quad*4+r, col(=b within tile)
    // =lrow -> thread owns h_new[b][n..n+4), n = n0 + nt*16 + quad*4.
    unsigned short* hdst = hbuf + (size_t)((t + 1) & 1) * (BATCH * HIDDEN);
    unsigned long long pk[4];
    float vv[4][4];
#pragma unroll
    for (int nt = 0; nt < 4; ++nt) {
      int n = n0 + nt * 16 + quad * 4;
      vv[nt][0] = tanh_fast(xv[nt].x + acc[nt][0]);
      vv[nt][1] = tanh_fast(xv[nt].y + acc[nt][1]);
      vv[nt][2] = tanh_fast(xv[nt].z + acc[nt][2]);
      vv[nt][3] = tanh_fast(xv[nt].w + acc[nt][3]);
      pk[nt] = (unsigned long long)f2bf(vv[nt][0])
             | ((unsigned long long)f2bf(vv[nt][1]) << 16)
             | ((unsigned long long)f2bf(vv[nt][2]) << 32)
             | ((unsigned long long)f2bf(vv[nt][3]) << 48);
      // sc1 store: lands at the coherence point, visible to all XCDs once
      // vmcnt acks -- no wbL2 needed.
      __hip_atomic_store((unsigned long long*)&hdst[(size_t)b * HIDDEN + n],
                         pk[nt], __ATOMIC_RELAXED, __HIP_MEMORY_SCOPE_AGENT);
    }

    // Order h stores before the arrival, then publish. outH/hlast go after
    // the arrival: they are only read by later dispatches (kernel-boundary
    // flush handles visibility), so keep them off the serial chain.
    asm volatile("s_waitcnt vmcnt(0)" ::: "memory");
    if (lane == 0)
      __hip_atomic_fetch_add(&bar[t], 1, __ATOMIC_RELAXED,
                             __HIP_MEMORY_SCOPE_AGENT);

#pragma unroll
    for (int nt = 0; nt < 4; ++nt) {
      int n = n0 + nt * 16 + quad * 4;
      *(unsigned long long*)&outH[(size_t)(b * TSTEPS + t) * HIDDEN + n] = pk[nt];
      if (t == TSTEPS - 1) {
        float4 o; o.x = vv[nt][0]; o.y = vv[nt][1]; o.z = vv[nt][2]; o.w = vv[nt][3];
        *(float4*)&hlast[(size_t)b * HIDDEN + n] = o;
      }
    }
  }
}

// ---------------------------------------------------------------------------
// logits_gemm: C[32768][4096] fp32 = A[32768][512]bf16 * B[4096][512]bf16^T + bias
// 128x128 tile, BK=64, global_load_lds width 16, 4 waves x (4x4 16x16 tiles).
__global__ __launch_bounds__(256) void logits_gemm(
    const unsigned short* __restrict__ A,     // outH
    const unsigned short* __restrict__ B,     // W_fc bf16
    const float* __restrict__ bias,           // b_fc
    float* __restrict__ C) {
  __shared__ unsigned short lA[128 * 64];
  __shared__ unsigned short lB[128 * 64];

  const int tid  = threadIdx.x;
  const int wave = tid >> 6, lane = tid & 63;
  const int quad = lane >> 4, lrow = lane & 15;
  const int bx = blockIdx.x;
  const int m0 = (bx >> 5) * 128;   // 256 m-tiles
  const int n0 = (bx & 31) * 128;   // 32 n-tiles
  const int wm = wave & 1, wn = wave >> 1;
  const int lr8 = (lane & 7) * 8;   // k offset within staged chunk
  const int lrw = lane >> 3;        // row within 8-row stage group

  f32x4 acc[4][4];
#pragma unroll
  for (int i = 0; i < 4; ++i)
#pragma unroll
    for (int j = 0; j < 4; ++j) acc[i][j] = (f32x4){0.f, 0.f, 0.f, 0.f};

  for (int kk = 0; kk < 8; ++kk) {
    __syncthreads();
    const int kb = kk * 64;
#pragma unroll
    for (int s = 0; s < 4; ++s) {
      int rA = wave * 32 + s * 8;   // 8 rows per instr, 32 rows per wave
      async16(A + (size_t)(m0 + rA + lrw) * HIDDEN + kb + lr8, &lA[rA * 64]);
      async16(B + (size_t)(n0 + rA + lrw) * HIDDEN + kb + lr8, &lB[rA * 64]);
    }
    __syncthreads();
#pragma unroll
    for (int kc = 0; kc < 2; ++kc) {
      bf16x8 af[4], bq[4];
#pragma unroll
      for (int i = 0; i < 4; ++i) {
        af[i] = *(const bf16x8*)&lA[(wm * 64 + i * 16 + lrow) * 64 + kc * 32 + quad * 8];
        bq[i] = *(const bf16x8*)&lB[(wn * 64 + i * 16 + lrow) * 64 + kc * 32 + quad * 8];
      }
#pragma unroll
      for (int i = 0; i < 4; ++i)
#pragma unroll
        for (int j = 0; j < 4; ++j)
          acc[i][j] = __builtin_amdgcn_mfma_f32_16x16x32_bf16(af[i], bq[j], acc[i][j], 0, 0, 0);
    }
  }

#pragma unroll
  for (int i = 0; i < 4; ++i) {
    int row = m0 + wm * 64 + i * 16 + quad * 4;
#pragma unroll
    for (int j = 0; j < 4; ++j) {
      int col = n0 + wn * 64 + j * 16 + lrow;
      float bs = bias[col];
#pragma unroll
      for (int r = 0; r < 4; ++r)
        C[(size_t)(row + r) * VOCAB + col] = acc[i][j][r] + bs;
    }
  }
}

// ---------------------------------------------------------------------------
extern "C" void kernel_launch(void* const* d_in, const int* in_sizes, int n_in,
                              void* d_out, int out_size, void* d_ws, size_t ws_size,
                              hipStream_t stream) {
  const int*   inp    = (const int*)d_in[0];
  const float* hidden = (const float*)d_in[1];
  const float* W_ih   = (const float*)d_in[2];
  const float* W_hh   = (const float*)d_in[3];
  const float* b_ih   = (const float*)d_in[4];
  const float* b_hh   = (const float*)d_in[5];
  const float* W_fc   = (const float*)d_in[6];
  const float* b_fc   = (const float*)d_in[7];

  char* ws = (char*)d_ws;
  float*          Wb   = (float*)ws;                                  // 8 MB
  unsigned short* Wfcb = (unsigned short*)(ws + (8  << 20));          // 4 MB
  unsigned short* outH = (unsigned short*)(ws + (12 << 20));          // 32 MB
  unsigned short* hbuf = (unsigned short*)(ws + (44 << 20));          // 128 KB
  int*            bar  = (int*)(ws + (44 << 20) + (1 << 18));         // 2 KB

  float* logits = (float*)d_out;                                      // [B,T,V]
  float* hlast  = logits + (size_t)BATCH * TSTEPS * VOCAB;            // [1,B,H]

  prep_small<<<128, 256, 0, stream>>>(hidden, hbuf, bar);
  build_Wb<<<512, 256, 0, stream>>>(W_ih, b_ih, b_hh, Wb);
  conv_wfc<<<2048, 256, 0, stream>>>(W_fc, Wfcb);
  rnn_scan<<<NWG, 256, 0, stream>>>(W_hh, Wb, inp, hbuf, outH, hlast, bar);
  logits_gemm<<<8192, 256, 0, stream>>>(outH, Wfcb, b_fc, logits);
}

// Round 2
// 5032.690 us; speedup vs baseline: 1.0138x; 1.0138x over previous
//
#include <hip/hip_runtime.h>

#define VOCAB   4096
#define HIDDEN  512
#define BATCH   64
#define TSTEPS  512
#define NWG     32       // workgroups in the RNN scan (16 hidden cols each)

typedef short bf16x8 __attribute__((ext_vector_type(8)));   // 8 bf16 = 4 VGPRs
typedef float f32x4  __attribute__((ext_vector_type(4)));

// fp32 -> bf16 round-to-nearest-even (values are finite; no NaN path needed)
__device__ __forceinline__ unsigned short f2bf(float f) {
  unsigned int x = __float_as_uint(f);
  unsigned int r = (x + 0x7fffu + ((x >> 16) & 1u)) >> 16;
  return (unsigned short)r;
}

// tanh via hw exp + rcp: tanh(x) = 1 - 2/(exp(2x)+1). Rel err ~1e-6, far
// below the bf16 rounding already in the tolerance budget.
__device__ __forceinline__ float tanh_fast(float x) {
  float e = __expf(2.0f * x);
  return fmaf(-2.0f, __builtin_amdgcn_rcpf(e + 1.0f), 1.0f);
}

// async global->LDS, 16B per lane (used by logits_gemm only).
__device__ __forceinline__ void async16(const void* g, void* l) {
  __builtin_amdgcn_global_load_lds(
      (const __attribute__((address_space(1))) unsigned int*)g,
      (__attribute__((address_space(3))) unsigned int*)l, 16, 0, 0);
}

// ---------------------------------------------------------------------------
// prep_small: convert initial hidden (fp32) to bf16 hbuf[0] and zero the
// 4x512 per-(group,step) barrier counters (ws is poisoned 0xAA each launch).
// grid 128 x 256 = 32768 threads exactly.
__global__ void prep_small(const float* __restrict__ hidden,
                           unsigned short* __restrict__ hbuf,
                           int* __restrict__ bar) {
  int i = blockIdx.x * 256 + threadIdx.x;
  hbuf[i] = f2bf(hidden[i]);
  if (i < 4 * TSTEPS) bar[i] = 0;
}

// ---------------------------------------------------------------------------
// build_Wb: Wb[v][h] = W_ih[h][v] + b_ih[h] + b_hh[h]   (fp32, 4096x512)
// 64x64 LDS tile transpose. grid 512 (64 v-tiles x 8 h-tiles), block 256.
__global__ void build_Wb(const float* __restrict__ W_ih,
                         const float* __restrict__ b_ih,
                         const float* __restrict__ b_hh,
                         float* __restrict__ Wb) {
  __shared__ float t[64][65];
  int bx = blockIdx.x;
  int vt = bx & 63, ht = bx >> 6;
  int v0 = vt * 64, h0 = ht * 64;
  int tx = threadIdx.x & 15, ty = threadIdx.x >> 4;
#pragma unroll
  for (int a = 0; a < 4; ++a) {
    int h = h0 + ty + 16 * a;
    float4 v = *(const float4*)&W_ih[(size_t)h * VOCAB + v0 + tx * 4];
    t[ty + 16 * a][tx * 4 + 0] = v.x;
    t[ty + 16 * a][tx * 4 + 1] = v.y;
    t[ty + 16 * a][tx * 4 + 2] = v.z;
    t[ty + 16 * a][tx * 4 + 3] = v.w;
  }
  __syncthreads();
#pragma unroll
  for (int a = 0; a < 4; ++a) {
    int v = v0 + ty + 16 * a;
    int hh = h0 + tx * 4;
    float4 o;
    o.x = t[tx * 4 + 0][ty + 16 * a] + b_ih[hh + 0] + b_hh[hh + 0];
    o.y = t[tx * 4 + 1][ty + 16 * a] + b_ih[hh + 1] + b_hh[hh + 1];
    o.z = t[tx * 4 + 2][ty + 16 * a] + b_ih[hh + 2] + b_hh[hh + 2];
    o.w = t[tx * 4 + 3][ty + 16 * a] + b_ih[hh + 3] + b_hh[hh + 3];
    *(float4*)&Wb[(size_t)v * HIDDEN + hh] = o;
  }
}

// ---------------------------------------------------------------------------
// conv_wfc: W_fc fp32 -> bf16. 2097152 elems, 4/thread, grid 2048 x 256 exact.
__global__ void conv_wfc(const float* __restrict__ W, unsigned short* __restrict__ o) {
  int i = (blockIdx.x * 256 + threadIdx.x) * 4;
  float4 v = *(const float4*)&W[i];
  ushort4 u;
  u.x = f2bf(v.x); u.y = f2bf(v.y); u.z = f2bf(v.z); u.w = f2bf(v.w);
  *(ushort4*)&o[i] = u;
}

// ---------------------------------------------------------------------------
// rnn_scan v3: 32 WGs x 256 threads, WG owns hidden cols [16w, 16w+16).
// No LDS, no __syncthreads, no cache-maintenance ops in the loop.
//  - wfrag (16 x bf16x8 = 64 VGPRs): W_hh A-fragments, resident all kernel.
//  - 4 independent barrier nets, one per wave-id: wave group w only consumes
//    h rows [16w,16w+16) which only group w produces -> bar[w][t] counts to 32.
//  - h exchange entirely via relaxed agent-scope (sc1) ops: stores go to the
//    MALL (coherence point), loads read it; L2 never invalidated so Wb/inp
//    stay L2-warm. Publish order: h stores -> s_waitcnt vmcnt(0) -> add.
//  - xv (Wb gather) issued BEFORE the spin: depends only on idx prefetched
//    last step, so its MALL/HBM latency rides the barrier wait.
//  - outH nontemporal (no L2 pollution), issued after the arrival.
__global__ __launch_bounds__(256) void rnn_scan(
    const float* __restrict__ Whh,      // [512][512] fp32
    const float* __restrict__ Wb,       // [4096][512] fp32 (biases folded)
    const int* __restrict__ inp,        // [64][512]
    unsigned short* __restrict__ hbuf,  // [2][64][512] bf16
    unsigned short* __restrict__ outH,  // [32768][512] bf16  (row = b*T + t)
    float* __restrict__ hlast,          // [64][512] fp32 (d_out tail)
    int* __restrict__ bar) {            // [4][512] arrival counters (zeroed)
  const int tid  = threadIdx.x;
  const int wave = tid >> 6, lane = tid & 63;
  const int quad = lane >> 4, lrow = lane & 15;
  const int n0   = blockIdx.x * 16;     // WG's 16 hidden cols
  const int b    = wave * 16 + lrow;    // this thread's batch row

  // A-frags: lane holds Whh[n0+lrow][kc*32 + quad*8 + j], j=0..7 (bf16)
  bf16x8 wfrag[16];
  {
    const float* wsrc = Whh + (size_t)(n0 + lrow) * HIDDEN + quad * 8;
#pragma unroll
    for (int kc = 0; kc < 16; ++kc) {
      float4 f0 = *(const float4*)(wsrc + kc * 32);
      float4 f1 = *(const float4*)(wsrc + kc * 32 + 4);
      bf16x8 v;
      v[0] = (short)f2bf(f0.x); v[1] = (short)f2bf(f0.y);
      v[2] = (short)f2bf(f0.z); v[3] = (short)f2bf(f0.w);
      v[4] = (short)f2bf(f1.x); v[5] = (short)f2bf(f1.y);
      v[6] = (short)f2bf(f1.z); v[7] = (short)f2bf(f1.w);
      wfrag[kc] = v;
    }
  }

  int* mybar = bar + wave * TSTEPS;     // this wave group's counter row
  int idx = inp[b * TSTEPS];            // x index for t=0 (prefetched)

  for (int t = 0; t < TSTEPS; ++t) {
    // x for THIS step: independent of h_t -> issue before the spin so the
    // (possibly L2-miss) gather latency hides under the barrier wait.
    float4 xv = *(const float4*)&Wb[(size_t)idx * HIDDEN + n0 + quad * 4];
    if (t + 1 < TSTEPS) idx = inp[b * TSTEPS + t + 1];

    if (t > 0) {
      // Relaxed spin on this group's counter (sc1 read of the MALL-resident
      // line; no buffer_inv per poll). Bounded: fail loud, not hang.
      int lim = 1 << 20;
      while (__hip_atomic_load(&mybar[t - 1], __ATOMIC_RELAXED,
                               __HIP_MEMORY_SCOPE_AGENT) < NWG && --lim) {}
      asm volatile("" ::: "memory");  // keep h loads below the spin
    }

    // B-frags: h[b][quad*8 + kc*32 ..+8] via relaxed agent u64 loads (read
    // the coherence point where producers' sc1 stores landed).
    const unsigned long long* hp = (const unsigned long long*)
        (hbuf + (size_t)(t & 1) * (BATCH * HIDDEN) + (size_t)b * HIDDEN + quad * 8);
    unsigned long long hl[16][2];
#pragma unroll
    for (int kc = 0; kc < 16; ++kc) {
      hl[kc][0] = __hip_atomic_load(hp + kc * 8, __ATOMIC_RELAXED,
                                    __HIP_MEMORY_SCOPE_AGENT);
      hl[kc][1] = __hip_atomic_load(hp + kc * 8 + 1, __ATOMIC_RELAXED,
                                    __HIP_MEMORY_SCOPE_AGENT);
    }

    // 16 MFMAs as two interleaved 8-deep accumulator chains.
    f32x4 acc0 = {0.f, 0.f, 0.f, 0.f}, acc1 = {0.f, 0.f, 0.f, 0.f};
#pragma unroll
    for (int kc = 0; kc < 16; kc += 2) {
      union { unsigned long long u[2]; bf16x8 v; } h0, h1;
      h0.u[0] = hl[kc][0];     h0.u[1] = hl[kc][1];
      h1.u[0] = hl[kc + 1][0]; h1.u[1] = hl[kc + 1][1];
      acc0 = __builtin_amdgcn_mfma_f32_16x16x32_bf16(wfrag[kc],     h0.v, acc0, 0, 0, 0);
      acc1 = __builtin_amdgcn_mfma_f32_16x16x32_bf16(wfrag[kc + 1], h1.v, acc1, 0, 0, 0);
    }
    f32x4 acc = acc0 + acc1;

    // Epilogue. D layout: row(n within tile)=quad*4+r, col(b within tile)=lrow
    // -> this thread owns h_new[b][n0+quad*4 .. +4).
    const int n = n0 + quad * 4;
    float v0 = tanh_fast(xv.x + acc[0]);
    float v1 = tanh_fast(xv.y + acc[1]);
    float v2 = tanh_fast(xv.z + acc[2]);
    float v3 = tanh_fast(xv.w + acc[3]);
    unsigned long long pk = (unsigned long long)f2bf(v0)
                          | ((unsigned long long)f2bf(v1) << 16)
                          | ((unsigned long long)f2bf(v2) << 32)
                          | ((unsigned long long)f2bf(v3) << 48);

    unsigned short* hdst = hbuf + (size_t)((t + 1) & 1) * (BATCH * HIDDEN);
    __hip_atomic_store((unsigned long long*)&hdst[(size_t)b * HIDDEN + n], pk,
                       __ATOMIC_RELAXED, __HIP_MEMORY_SCOPE_AGENT);

    // Order the h store before the arrival, then publish (relaxed: vmcnt(0)
    // already guarantees the store reached the coherence point).
    asm volatile("s_waitcnt vmcnt(0)" ::: "memory");
    if (lane == 0)
      __hip_atomic_fetch_add(&mybar[t], 1, __ATOMIC_RELAXED,
                             __HIP_MEMORY_SCOPE_AGENT);

    // Off the critical chain: nontemporal (no L2 allocate -> Wb stays warm).
    __builtin_nontemporal_store(pk,
        (unsigned long long*)&outH[(size_t)(b * TSTEPS + t) * HIDDEN + n]);
    if (t == TSTEPS - 1) {
      float4 o; o.x = v0; o.y = v1; o.z = v2; o.w = v3;
      *(float4*)&hlast[(size_t)b * HIDDEN + n] = o;
    }
  }
}

// ---------------------------------------------------------------------------
// logits_gemm: C[32768][4096] fp32 = A[32768][512]bf16 * B[4096][512]bf16^T + bias
// 128x128 tile, BK=64, global_load_lds width 16, 4 waves x (4x4 16x16 tiles).
__global__ __launch_bounds__(256) void logits_gemm(
    const unsigned short* __restrict__ A,     // outH
    const unsigned short* __restrict__ B,     // W_fc bf16
    const float* __restrict__ bias,           // b_fc
    float* __restrict__ C) {
  __shared__ unsigned short lA[128 * 64];
  __shared__ unsigned short lB[128 * 64];

  const int tid  = threadIdx.x;
  const int wave = tid >> 6, lane = tid & 63;
  const int quad = lane >> 4, lrow = lane & 15;
  const int bx = blockIdx.x;
  const int m0 = (bx >> 5) * 128;   // 256 m-tiles
  const int n0 = (bx & 31) * 128;   // 32 n-tiles
  const int wm = wave & 1, wn = wave >> 1;
  const int lr8 = (lane & 7) * 8;   // k offset within staged chunk
  const int lrw = lane >> 3;        // row within 8-row stage group

  f32x4 acc[4][4];
#pragma unroll
  for (int i = 0; i < 4; ++i)
#pragma unroll
    for (int j = 0; j < 4; ++j) acc[i][j] = (f32x4){0.f, 0.f, 0.f, 0.f};

  for (int kk = 0; kk < 8; ++kk) {
    __syncthreads();
    const int kb = kk * 64;
#pragma unroll
    for (int s = 0; s < 4; ++s) {
      int rA = wave * 32 + s * 8;   // 8 rows per instr, 32 rows per wave
      async16(A + (size_t)(m0 + rA + lrw) * HIDDEN + kb + lr8, &lA[rA * 64]);
      async16(B + (size_t)(n0 + rA + lrw) * HIDDEN + kb + lr8, &lB[rA * 64]);
    }
    __syncthreads();
#pragma unroll
    for (int kc = 0; kc < 2; ++kc) {
      bf16x8 af[4], bq[4];
#pragma unroll
      for (int i = 0; i < 4; ++i) {
        af[i] = *(const bf16x8*)&lA[(wm * 64 + i * 16 + lrow) * 64 + kc * 32 + quad * 8];
        bq[i] = *(const bf16x8*)&lB[(wn * 64 + i * 16 + lrow) * 64 + kc * 32 + quad * 8];
      }
#pragma unroll
      for (int i = 0; i < 4; ++i)
#pragma unroll
        for (int j = 0; j < 4; ++j)
          acc[i][j] = __builtin_amdgcn_mfma_f32_16x16x32_bf16(af[i], bq[j], acc[i][j], 0, 0, 0);
    }
  }

#pragma unroll
  for (int i = 0; i < 4; ++i) {
    int row = m0 + wm * 64 + i * 16 + quad * 4;
#pragma unroll
    for (int j = 0; j < 4; ++j) {
      int col = n0 + wn * 64 + j * 16 + lrow;
      float bs = bias[col];
#pragma unroll
      for (int r = 0; r < 4; ++r)
        C[(size_t)(row + r) * VOCAB + col] = acc[i][j][r] + bs;
    }
  }
}

// ---------------------------------------------------------------------------
extern "C" void kernel_launch(void* const* d_in, const int* in_sizes, int n_in,
                              void* d_out, int out_size, void* d_ws, size_t ws_size,
                              hipStream_t stream) {
  const int*   inp    = (const int*)d_in[0];
  const float* hidden = (const float*)d_in[1];
  const float* W_ih   = (const float*)d_in[2];
  const float* W_hh   = (const float*)d_in[3];
  const float* b_ih   = (const float*)d_in[4];
  const float* b_hh   = (const float*)d_in[5];
  const float* W_fc   = (const float*)d_in[6];
  const float* b_fc   = (const float*)d_in[7];

  char* ws = (char*)d_ws;
  float*          Wb   = (float*)ws;                                  // 8 MB
  unsigned short* Wfcb = (unsigned short*)(ws + (8  << 20));          // 4 MB
  unsigned short* outH = (unsigned short*)(ws + (12 << 20));          // 32 MB
  unsigned short* hbuf = (unsigned short*)(ws + (44 << 20));          // 128 KB
  int*            bar  = (int*)(ws + (44 << 20) + (1 << 18));         // 8 KB

  float* logits = (float*)d_out;                                      // [B,T,V]
  float* hlast  = logits + (size_t)BATCH * TSTEPS * VOCAB;            // [1,B,H]

  prep_small<<<128, 256, 0, stream>>>(hidden, hbuf, bar);
  build_Wb<<<512, 256, 0, stream>>>(W_ih, b_ih, b_hh, Wb);
  conv_wfc<<<2048, 256, 0, stream>>>(W_fc, Wfcb);
  rnn_scan<<<NWG, 256, 0, stream>>>(W_hh, Wb, inp, hbuf, outH, hlast, bar);
  logits_gemm<<<8192, 256, 0, stream>>>(outH, Wfcb, b_fc, logits);
}

// Round 3
// 4736.289 us; speedup vs baseline: 1.0772x; 1.0626x over previous
//
#include <hip/hip_runtime.h>

#define VOCAB   4096
#define HIDDEN  512
#define BATCH   64
#define TSTEPS  512
#define NWG     32       // workgroups in the RNN scan (16 hidden cols each)

typedef short bf16x8 __attribute__((ext_vector_type(8)));   // 8 bf16 = 4 VGPRs
typedef float f32x4  __attribute__((ext_vector_type(4)));

// fp32 -> bf16 round-to-nearest-even (values are finite; no NaN path needed)
__device__ __forceinline__ unsigned short f2bf(float f) {
  unsigned int x = __float_as_uint(f);
  unsigned int r = (x + 0x7fffu + ((x >> 16) & 1u)) >> 16;
  return (unsigned short)r;
}

// tanh via hw exp + rcp: tanh(x) = 1 - 2/(exp(2x)+1). Rel err ~1e-6, far
// below the bf16 rounding already in the tolerance budget.
__device__ __forceinline__ float tanh_fast(float x) {
  float e = __expf(2.0f * x);
  return fmaf(-2.0f, __builtin_amdgcn_rcpf(e + 1.0f), 1.0f);
}

// async global->LDS, 16B per lane (used by logits_gemm only).
__device__ __forceinline__ void async16(const void* g, void* l) {
  __builtin_amdgcn_global_load_lds(
      (const __attribute__((address_space(1))) unsigned int*)g,
      (__attribute__((address_space(3))) unsigned int*)l, 16, 0, 0);
}

// ---------------------------------------------------------------------------
// prep_small: convert initial hidden (fp32) to bf16 hbuf[0] and zero the
// flag array [2][4][32] ints (ws is poisoned 0xAA each launch).
// grid 128 x 256 = 32768 threads exactly.
__global__ void prep_small(const float* __restrict__ hidden,
                           unsigned short* __restrict__ hbuf,
                           int* __restrict__ flag) {
  int i = blockIdx.x * 256 + threadIdx.x;
  hbuf[i] = f2bf(hidden[i]);
  if (i < 2 * 4 * 32) flag[i] = 0;
}

// ---------------------------------------------------------------------------
// build_Wb: Wb[v][h] = W_ih[h][v] + b_ih[h] + b_hh[h]   (fp32, 4096x512)
// 64x64 LDS tile transpose. grid 512 (64 v-tiles x 8 h-tiles), block 256.
__global__ void build_Wb(const float* __restrict__ W_ih,
                         const float* __restrict__ b_ih,
                         const float* __restrict__ b_hh,
                         float* __restrict__ Wb) {
  __shared__ float t[64][65];
  int bx = blockIdx.x;
  int vt = bx & 63, ht = bx >> 6;
  int v0 = vt * 64, h0 = ht * 64;
  int tx = threadIdx.x & 15, ty = threadIdx.x >> 4;
#pragma unroll
  for (int a = 0; a < 4; ++a) {
    int h = h0 + ty + 16 * a;
    float4 v = *(const float4*)&W_ih[(size_t)h * VOCAB + v0 + tx * 4];
    t[ty + 16 * a][tx * 4 + 0] = v.x;
    t[ty + 16 * a][tx * 4 + 1] = v.y;
    t[ty + 16 * a][tx * 4 + 2] = v.z;
    t[ty + 16 * a][tx * 4 + 3] = v.w;
  }
  __syncthreads();
#pragma unroll
  for (int a = 0; a < 4; ++a) {
    int v = v0 + ty + 16 * a;
    int hh = h0 + tx * 4;
    float4 o;
    o.x = t[tx * 4 + 0][ty + 16 * a] + b_ih[hh + 0] + b_hh[hh + 0];
    o.y = t[tx * 4 + 1][ty + 16 * a] + b_ih[hh + 1] + b_hh[hh + 1];
    o.z = t[tx * 4 + 2][ty + 16 * a] + b_ih[hh + 2] + b_hh[hh + 2];
    o.w = t[tx * 4 + 3][ty + 16 * a] + b_ih[hh + 3] + b_hh[hh + 3];
    *(float4*)&Wb[(size_t)v * HIDDEN + hh] = o;
  }
}

// ---------------------------------------------------------------------------
// conv_wfc: W_fc fp32 -> bf16. 2097152 elems, 4/thread, grid 2048 x 256 exact.
__global__ void conv_wfc(const float* __restrict__ W, unsigned short* __restrict__ o) {
  int i = (blockIdx.x * 256 + threadIdx.x) * 4;
  float4 v = *(const float4*)&W[i];
  ushort4 u;
  u.x = f2bf(v.x); u.y = f2bf(v.y); u.z = f2bf(v.z); u.w = f2bf(v.w);
  *(ushort4*)&o[i] = u;
}

// ---------------------------------------------------------------------------
// rnn_scan v4: identical to v3 EXCEPT the barrier is RMW-free.
//  - 32 WGs x 256 threads, WG owns hidden cols [16w, 16w+16). No LDS, no
//    __syncthreads, no cache-maintenance in the loop.
//  - 4 independent nets (one per wave-id): net w exchanges only h rows
//    [16w,16w+16), produced and consumed solely by wave w of each WG.
//  - Publish: one 8B sc1 h-store -> s_waitcnt vmcnt(0) (h at coherence
//    point) -> lane0 stores flag[t&1][wave][wg] = t+1 (plain relaxed store;
//    32 distinct dwords of one 128B line -> stores merge, NO atomic RMW).
//  - Poll: one vector load/iteration -- lanes read all 32 flags of the net,
//    __all(f == t). Reads never take line ownership; no RMW serialization.
//  - Flag visible => h visible (h completed before flag issued).
//  - xv (Wb gather) + idx prefetched before the spin so their latency rides
//    the barrier wait; outH nontemporal after the publish.
__global__ __launch_bounds__(256) void rnn_scan(
    const float* __restrict__ Whh,      // [512][512] fp32
    const float* __restrict__ Wb,       // [4096][512] fp32 (biases folded)
    const int* __restrict__ inp,        // [64][512]
    unsigned short* __restrict__ hbuf,  // [2][64][512] bf16
    unsigned short* __restrict__ outH,  // [32768][512] bf16  (row = b*T + t)
    float* __restrict__ hlast,          // [64][512] fp32 (d_out tail)
    int* __restrict__ flag) {           // [2][4][32] step flags (pre-zeroed)
  const int tid  = threadIdx.x;
  const int wave = tid >> 6, lane = tid & 63;
  const int quad = lane >> 4, lrow = lane & 15;
  const int n0   = blockIdx.x * 16;     // WG's 16 hidden cols
  const int b    = wave * 16 + lrow;    // this thread's batch row

  // A-frags: lane holds Whh[n0+lrow][kc*32 + quad*8 + j], j=0..7 (bf16)
  bf16x8 wfrag[16];
  {
    const float* wsrc = Whh + (size_t)(n0 + lrow) * HIDDEN + quad * 8;
#pragma unroll
    for (int kc = 0; kc < 16; ++kc) {
      float4 f0 = *(const float4*)(wsrc + kc * 32);
      float4 f1 = *(const float4*)(wsrc + kc * 32 + 4);
      bf16x8 v;
      v[0] = (short)f2bf(f0.x); v[1] = (short)f2bf(f0.y);
      v[2] = (short)f2bf(f0.z); v[3] = (short)f2bf(f0.w);
      v[4] = (short)f2bf(f1.x); v[5] = (short)f2bf(f1.y);
      v[6] = (short)f2bf(f1.z); v[7] = (short)f2bf(f1.w);
      wfrag[kc] = v;
    }
  }

  int idx = inp[b * TSTEPS];            // x index for t=0 (prefetched)

  for (int t = 0; t < TSTEPS; ++t) {
    // x for THIS step: independent of h_t -> issue before the spin so the
    // gather latency hides under the barrier wait (lands in registers; no
    // cache-residency dependence).
    float4 xv = *(const float4*)&Wb[(size_t)idx * HIDDEN + n0 + quad * 4];
    if (t + 1 < TSTEPS) idx = inp[b * TSTEPS + t + 1];

    if (t > 0) {
      // RMW-free spin: one 128B-line vector load reads all 32 flags of this
      // wave's net; done when every producer has stored value t. Bounded:
      // fail loud (wrong data), not hang.
      const int* fl = flag + ((t - 1) & 1) * (4 * 32) + wave * 32;
      int lim = 1 << 20;
      int f;
      do {
        f = __hip_atomic_load(&fl[lane & 31], __ATOMIC_RELAXED,
                              __HIP_MEMORY_SCOPE_AGENT);
      } while (!__all(f == t) && --lim);
      asm volatile("" ::: "memory");  // keep h loads below the spin
    }

    // B-frags: h[b][kc*32 + quad*8 ..+8] via relaxed agent u64 loads (read
    // the coherence point where producers' stores landed).
    const unsigned long long* hp = (const unsigned long long*)
        (hbuf + (size_t)(t & 1) * (BATCH * HIDDEN) + (size_t)b * HIDDEN + quad * 8);
    unsigned long long hl[16][2];
#pragma unroll
    for (int kc = 0; kc < 16; ++kc) {
      hl[kc][0] = __hip_atomic_load(hp + kc * 8, __ATOMIC_RELAXED,
                                    __HIP_MEMORY_SCOPE_AGENT);
      hl[kc][1] = __hip_atomic_load(hp + kc * 8 + 1, __ATOMIC_RELAXED,
                                    __HIP_MEMORY_SCOPE_AGENT);
    }

    // 16 MFMAs as two interleaved 8-deep accumulator chains.
    f32x4 acc0 = {0.f, 0.f, 0.f, 0.f}, acc1 = {0.f, 0.f, 0.f, 0.f};
#pragma unroll
    for (int kc = 0; kc < 16; kc += 2) {
      union { unsigned long long u[2]; bf16x8 v; } h0, h1;
      h0.u[0] = hl[kc][0];     h0.u[1] = hl[kc][1];
      h1.u[0] = hl[kc + 1][0]; h1.u[1] = hl[kc + 1][1];
      acc0 = __builtin_amdgcn_mfma_f32_16x16x32_bf16(wfrag[kc],     h0.v, acc0, 0, 0, 0);
      acc1 = __builtin_amdgcn_mfma_f32_16x16x32_bf16(wfrag[kc + 1], h1.v, acc1, 0, 0, 0);
    }
    f32x4 acc = acc0 + acc1;

    // Epilogue. D layout: row(n within tile)=quad*4+r, col(b within tile)=lrow
    // -> this thread owns h_new[b][n0+quad*4 .. +4).
    const int n = n0 + quad * 4;
    float v0 = tanh_fast(xv.x + acc[0]);
    float v1 = tanh_fast(xv.y + acc[1]);
    float v2 = tanh_fast(xv.z + acc[2]);
    float v3 = tanh_fast(xv.w + acc[3]);
    unsigned long long pk = (unsigned long long)f2bf(v0)
                          | ((unsigned long long)f2bf(v1) << 16)
                          | ((unsigned long long)f2bf(v2) << 32)
                          | ((unsigned long long)f2bf(v3) << 48);

    unsigned short* hdst = hbuf + (size_t)((t + 1) & 1) * (BATCH * HIDDEN);
    __hip_atomic_store((unsigned long long*)&hdst[(size_t)b * HIDDEN + n], pk,
                       __ATOMIC_RELAXED, __HIP_MEMORY_SCOPE_AGENT);

    // h store completed at the coherence point BEFORE the flag store is
    // issued -> flag visible implies h visible. No RMW, no fence, no wbL2.
    asm volatile("s_waitcnt vmcnt(0)" ::: "memory");
    if (lane == 0)
      __hip_atomic_store(&flag[(t & 1) * (4 * 32) + wave * 32 + blockIdx.x],
                         t + 1, __ATOMIC_RELAXED, __HIP_MEMORY_SCOPE_AGENT);

    // Off the critical chain: nontemporal (no L2 allocate).
    __builtin_nontemporal_store(pk,
        (unsigned long long*)&outH[(size_t)(b * TSTEPS + t) * HIDDEN + n]);
    if (t == TSTEPS - 1) {
      float4 o; o.x = v0; o.y = v1; o.z = v2; o.w = v3;
      *(float4*)&hlast[(size_t)b * HIDDEN + n] = o;
    }
  }
}

// ---------------------------------------------------------------------------
// logits_gemm: C[32768][4096] fp32 = A[32768][512]bf16 * B[4096][512]bf16^T + bias
// 128x128 tile, BK=64, global_load_lds width 16, 4 waves x (4x4 16x16 tiles).
__global__ __launch_bounds__(256) void logits_gemm(
    const unsigned short* __restrict__ A,     // outH
    const unsigned short* __restrict__ B,     // W_fc bf16
    const float* __restrict__ bias,           // b_fc
    float* __restrict__ C) {
  __shared__ unsigned short lA[128 * 64];
  __shared__ unsigned short lB[128 * 64];

  const int tid  = threadIdx.x;
  const int wave = tid >> 6, lane = tid & 63;
  const int quad = lane >> 4, lrow = lane & 15;
  const int bx = blockIdx.x;
  const int m0 = (bx >> 5) * 128;   // 256 m-tiles
  const int n0 = (bx & 31) * 128;   // 32 n-tiles
  const int wm = wave & 1, wn = wave >> 1;
  const int lr8 = (lane & 7) * 8;   // k offset within staged chunk
  const int lrw = lane >> 3;        // row within 8-row stage group

  f32x4 acc[4][4];
#pragma unroll
  for (int i = 0; i < 4; ++i)
#pragma unroll
    for (int j = 0; j < 4; ++j) acc[i][j] = (f32x4){0.f, 0.f, 0.f, 0.f};

  for (int kk = 0; kk < 8; ++kk) {
    __syncthreads();
    const int kb = kk * 64;
#pragma unroll
    for (int s = 0; s < 4; ++s) {
      int rA = wave * 32 + s * 8;   // 8 rows per instr, 32 rows per wave
      async16(A + (size_t)(m0 + rA + lrw) * HIDDEN + kb + lr8, &lA[rA * 64]);
      async16(B + (size_t)(n0 + rA + lrw) * HIDDEN + kb + lr8, &lB[rA * 64]);
    }
    __syncthreads();
#pragma unroll
    for (int kc = 0; kc < 2; ++kc) {
      bf16x8 af[4], bq[4];
#pragma unroll
      for (int i = 0; i < 4; ++i) {
        af[i] = *(const bf16x8*)&lA[(wm * 64 + i * 16 + lrow) * 64 + kc * 32 + quad * 8];
        bq[i] = *(const bf16x8*)&lB[(wn * 64 + i * 16 + lrow) * 64 + kc * 32 + quad * 8];
      }
#pragma unroll
      for (int i = 0; i < 4; ++i)
#pragma unroll
        for (int j = 0; j < 4; ++j)
          acc[i][j] = __builtin_amdgcn_mfma_f32_16x16x32_bf16(af[i], bq[j], acc[i][j], 0, 0, 0);
    }
  }

#pragma unroll
  for (int i = 0; i < 4; ++i) {
    int row = m0 + wm * 64 + i * 16 + quad * 4;
#pragma unroll
    for (int j = 0; j < 4; ++j) {
      int col = n0 + wn * 64 + j * 16 + lrow;
      float bs = bias[col];
#pragma unroll
      for (int r = 0; r < 4; ++r)
        C[(size_t)(row + r) * VOCAB + col] = acc[i][j][r] + bs;
    }
  }
}

// ---------------------------------------------------------------------------
extern "C" void kernel_launch(void* const* d_in, const int* in_sizes, int n_in,
                              void* d_out, int out_size, void* d_ws, size_t ws_size,
                              hipStream_t stream) {
  const int*   inp    = (const int*)d_in[0];
  const float* hidden = (const float*)d_in[1];
  const float* W_ih   = (const float*)d_in[2];
  const float* W_hh   = (const float*)d_in[3];
  const float* b_ih   = (const float*)d_in[4];
  const float* b_hh   = (const float*)d_in[5];
  const float* W_fc   = (const float*)d_in[6];
  const float* b_fc   = (const float*)d_in[7];

  char* ws = (char*)d_ws;
  float*          Wb   = (float*)ws;                                  // 8 MB
  unsigned short* Wfcb = (unsigned short*)(ws + (8  << 20));          // 4 MB
  unsigned short* outH = (unsigned short*)(ws + (12 << 20));          // 32 MB
  unsigned short* hbuf = (unsigned short*)(ws + (44 << 20));          // 128 KB
  int*            flag = (int*)(ws + (44 << 20) + (1 << 18));         // 1 KB

  float* logits = (float*)d_out;                                      // [B,T,V]
  float* hlast  = logits + (size_t)BATCH * TSTEPS * VOCAB;            // [1,B,H]

  prep_small<<<128, 256, 0, stream>>>(hidden, hbuf, flag);
  build_Wb<<<512, 256, 0, stream>>>(W_ih, b_ih, b_hh, Wb);
  conv_wfc<<<2048, 256, 0, stream>>>(W_fc, Wfcb);
  rnn_scan<<<NWG, 256, 0, stream>>>(W_hh, Wb, inp, hbuf, outH, hlast, flag);
  logits_gemm<<<8192, 256, 0, stream>>>(outH, Wfcb, b_fc, logits);
}

// Round 4
// 3433.451 us; speedup vs baseline: 1.4860x; 1.3795x over previous
//
#include <hip/hip_runtime.h>

#define VOCAB   4096
#define HIDDEN  512
#define BATCH   64
#define TSTEPS  512
#define NSCAN   4        // scan WGs: batch-split, 16 batches each,独立 — no comm

typedef short bf16x8 __attribute__((ext_vector_type(8)));   // 8 bf16 = 4 VGPRs
typedef float f32x4  __attribute__((ext_vector_type(4)));

// fp32 -> bf16 round-to-nearest-even (values are finite; no NaN path needed)
__device__ __forceinline__ unsigned short f2bf(float f) {
  unsigned int x = __float_as_uint(f);
  unsigned int r = (x + 0x7fffu + ((x >> 16) & 1u)) >> 16;
  return (unsigned short)r;
}

// tanh via hw exp + rcp: tanh(x) = 1 - 2/(exp(2x)+1). Rel err ~1e-6.
__device__ __forceinline__ float tanh_fast(float x) {
  float e = __expf(2.0f * x);
  return fmaf(-2.0f, __builtin_amdgcn_rcpf(e + 1.0f), 1.0f);
}

// async global->LDS, 16B per lane (used by logits_gemm only).
__device__ __forceinline__ void async16(const void* g, void* l) {
  __builtin_amdgcn_global_load_lds(
      (const __attribute__((address_space(1))) unsigned int*)g,
      (__attribute__((address_space(3))) unsigned int*)l, 16, 0, 0);
}

// ---------------------------------------------------------------------------
// build_Wb: Wb[v][h] = W_ih[h][v] + b_ih[h] + b_hh[h]   (fp32, 4096x512)
// 64x64 LDS tile transpose. grid 512 (64 v-tiles x 8 h-tiles), block 256.
__global__ void build_Wb(const float* __restrict__ W_ih,
                         const float* __restrict__ b_ih,
                         const float* __restrict__ b_hh,
                         float* __restrict__ Wb) {
  __shared__ float t[64][65];
  int bx = blockIdx.x;
  int vt = bx & 63, ht = bx >> 6;
  int v0 = vt * 64, h0 = ht * 64;
  int tx = threadIdx.x & 15, ty = threadIdx.x >> 4;
#pragma unroll
  for (int a = 0; a < 4; ++a) {
    int h = h0 + ty + 16 * a;
    float4 v = *(const float4*)&W_ih[(size_t)h * VOCAB + v0 + tx * 4];
    t[ty + 16 * a][tx * 4 + 0] = v.x;
    t[ty + 16 * a][tx * 4 + 1] = v.y;
    t[ty + 16 * a][tx * 4 + 2] = v.z;
    t[ty + 16 * a][tx * 4 + 3] = v.w;
  }
  __syncthreads();
#pragma unroll
  for (int a = 0; a < 4; ++a) {
    int v = v0 + ty + 16 * a;
    int hh = h0 + tx * 4;
    float4 o;
    o.x = t[tx * 4 + 0][ty + 16 * a] + b_ih[hh + 0] + b_hh[hh + 0];
    o.y = t[tx * 4 + 1][ty + 16 * a] + b_ih[hh + 1] + b_hh[hh + 1];
    o.z = t[tx * 4 + 2][ty + 16 * a] + b_ih[hh + 2] + b_hh[hh + 2];
    o.w = t[tx * 4 + 3][ty + 16 * a] + b_ih[hh + 3] + b_hh[hh + 3];
    *(float4*)&Wb[(size_t)v * HIDDEN + hh] = o;
  }
}

// ---------------------------------------------------------------------------
// conv_wfc: W_fc fp32 -> bf16. 2097152 elems, 4/thread, grid 2048 x 256 exact.
__global__ void conv_wfc(const float* __restrict__ W, unsigned short* __restrict__ o) {
  int i = (blockIdx.x * 256 + threadIdx.x) * 4;
  float4 v = *(const float4*)&W[i];
  ushort4 u;
  u.x = f2bf(v.x); u.y = f2bf(v.y); u.z = f2bf(v.z); u.w = f2bf(v.w);
  *(ushort4*)&o[i] = u;
}

// ---------------------------------------------------------------------------
// prep_Wf: W_hh fp32 -> bf16 in MFMA-frag-linear layout.
// Wf[frag f = ntg*16+kc][lane][8]: lane (quad,lrow) holds
//   W_hh[n = ntg*16+lrow][k = kc*32 + quad*8 + j], j=0..7.
// A wave's frag load is then 64 consecutive 16B chunks (perfectly coalesced).
// 512 frags x 64 lanes = 32768 threads: grid 128 x 256 exact.
__global__ void prep_Wf(const float* __restrict__ Whh, unsigned short* __restrict__ Wf) {
  int i = blockIdx.x * 256 + threadIdx.x;
  int lane = i & 63, fr = i >> 6;
  int kc = fr & 15, ntg = fr >> 4;
  int n = ntg * 16 + (lane & 15);
  int k = kc * 32 + (lane >> 4) * 8;
  const float* src = Whh + (size_t)n * HIDDEN + k;
  float4 f0 = *(const float4*)src;
  float4 f1 = *(const float4*)(src + 4);
  bf16x8 v;
  v[0] = (short)f2bf(f0.x); v[1] = (short)f2bf(f0.y);
  v[2] = (short)f2bf(f0.z); v[3] = (short)f2bf(f0.w);
  v[4] = (short)f2bf(f1.x); v[5] = (short)f2bf(f1.y);
  v[6] = (short)f2bf(f1.z); v[7] = (short)f2bf(f1.w);
  *(bf16x8*)(Wf + (size_t)i * 8) = v;
}

// ---------------------------------------------------------------------------
// rnn_scan v5: BATCH-SPLIT. 4 WGs x 512 threads (8 waves); WG g owns batches
// [16g,16g+16) for the ENTIRE scan -> zero inter-WG communication: no
// atomics, no flags, no fabric round-trips. h ([16][512] bf16, 16KB) lives
// in LDS, double-buffered; one intra-CU barrier per step.
//  - wave w computes n-cols [64w,64w+64) (4 n-tiles) for all 16 batches.
//  - W_hh: half resident in VGPRs (wr[32] frags = 128 VGPR: n-tiles 0,1 of
//    the wave's slice), half streamed from L2 per step (n-tiles 2,3: 32
//    frags = 32KB/wave = 256KB/CU/step; frag-linear coalesced dwordx4,
//    4-frag double-buffered chunks). Stream set is identical across WGs ->
//    L2-resident per XCD after step 0.
//  - h LDS tile XOR-swizzled (byte ^= (row&7)<<4) so the stride-1024B
//    b128 frag reads hit the 8-cycle floor (16-way conflict otherwise).
//  - barrier = raw "s_waitcnt lgkmcnt(0); s_barrier" (no vmcnt drain):
//    outH/hlast stores stay in flight across steps.
//  - MFMA operand scheme (A=W frag, B=h frag, D row=n col=b) carried over
//    verbatim from the harness-verified v2-v4 kernels.
__global__ __launch_bounds__(512) void rnn_scan(
    const unsigned short* __restrict__ Wf,   // [512 frags][64][8] bf16
    const float* __restrict__ Wb,            // [4096][512] fp32 (biases folded)
    const int* __restrict__ inp,             // [64][512]
    const float* __restrict__ hidden,        // [1][64][512] fp32
    unsigned short* __restrict__ outH,       // [32768][512] bf16 (row=b*T+t)
    float* __restrict__ hlast) {             // [64][512] fp32 (d_out tail)
  __shared__ unsigned short hls[2 * 16 * HIDDEN];   // 2 x 16KB, swizzled rows
  char* lb = (char*)hls;

  const int tid  = threadIdx.x;
  const int wv   = tid >> 6, lane = tid & 63;
  const int quad = lane >> 4, lrow = lane & 15;
  const int bg   = blockIdx.x * 16;     // WG's batch base
  const int n0   = wv * 64;             // wave's n-slice
  const int b    = bg + lrow;           // this thread's batch (B-frag col)

  // per-wave frag base: frag f_local (=nt*16+kc, nt 0..3) at wsb + f_local*512
  const unsigned short* wsb = Wf + (size_t)wv * 32768 + lane * 8;

  // resident half: n-tiles 0,1 (frags 0..31) -> 128 VGPRs
  bf16x8 wr[32];
#pragma unroll
  for (int j = 0; j < 32; ++j) wr[j] = *(const bf16x8*)(wsb + j * 512);

  // h0 -> LDS buf0 (bf16, swizzled). 512 threads x 16 elems.
  {
    int r = tid >> 5;                   // local batch row 0..15
    int c = (tid & 31) * 16;            // element col
    const float* src = hidden + (size_t)(bg + r) * HIDDEN + c;
    float4 f0 = *(const float4*)(src);
    float4 f1 = *(const float4*)(src + 4);
    float4 f2 = *(const float4*)(src + 8);
    float4 f3 = *(const float4*)(src + 12);
    bf16x8 p0, p1;
    p0[0] = (short)f2bf(f0.x); p0[1] = (short)f2bf(f0.y);
    p0[2] = (short)f2bf(f0.z); p0[3] = (short)f2bf(f0.w);
    p0[4] = (short)f2bf(f1.x); p0[5] = (short)f2bf(f1.y);
    p0[6] = (short)f2bf(f1.z); p0[7] = (short)f2bf(f1.w);
    p1[0] = (short)f2bf(f2.x); p1[1] = (short)f2bf(f2.y);
    p1[2] = (short)f2bf(f2.z); p1[3] = (short)f2bf(f2.w);
    p1[4] = (short)f2bf(f3.x); p1[5] = (short)f2bf(f3.y);
    p1[6] = (short)f2bf(f3.z); p1[7] = (short)f2bf(f3.w);
    int base = r * 1024 + c * 2;
    int sw = (r & 7) << 4;
    *(bf16x8*)(lb + (base ^ sw)) = p0;
    *(bf16x8*)(lb + ((base + 16) ^ sw)) = p1;
  }
  __syncthreads();

  const int rbase = lrow * 1024 + quad * 16;   // h-frag byte base (row,quad)
  const int swz   = (lrow & 7) << 4;           // bank swizzle

#define LDSREAD(KC) (*(const bf16x8*)(lb + lcur + ((rbase + (KC) * 64) ^ swz)))
#define ISSUE(BUF, FB) do { _Pragma("unroll") \
    for (int j_ = 0; j_ < 4; ++j_) BUF[j_] = *(const bf16x8*)(wsb + ((FB) + j_) * 512); \
  } while (0)
#define CONSUME(BUF, ACC, KB) do { _Pragma("unroll") \
    for (int j_ = 0; j_ < 4; ++j_) { \
      bf16x8 hf_ = LDSREAD((KB) + j_); \
      ACC = __builtin_amdgcn_mfma_f32_16x16x32_bf16(BUF[j_], hf_, ACC, 0, 0, 0); \
    } } while (0)
#define EPI(ACC, NT) do { \
    const int n_ = n0 + (NT) * 16 + quad * 4; \
    float e0 = tanh_fast(xv[NT].x + (ACC)[0]); \
    float e1 = tanh_fast(xv[NT].y + (ACC)[1]); \
    float e2 = tanh_fast(xv[NT].z + (ACC)[2]); \
    float e3 = tanh_fast(xv[NT].w + (ACC)[3]); \
    unsigned long long pk = (unsigned long long)f2bf(e0) \
        | ((unsigned long long)f2bf(e1) << 16) \
        | ((unsigned long long)f2bf(e2) << 32) \
        | ((unsigned long long)f2bf(e3) << 48); \
    *(unsigned long long*)(lb + lnext + ((lrow * 1024 + n_ * 2) ^ swz)) = pk; \
    __builtin_nontemporal_store(pk, \
        (unsigned long long*)&outH[(size_t)(b * TSTEPS + t) * HIDDEN + n_]); \
    if (t == TSTEPS - 1) { \
      float4 o_; o_.x = e0; o_.y = e1; o_.z = e2; o_.w = e3; \
      *(float4*)&hlast[(size_t)b * HIDDEN + n_] = o_; \
    } \
  } while (0)

  int idxN = inp[b * TSTEPS];           // x index for t=0 (prefetched)

  for (int t = 0; t < TSTEPS; ++t) {
    const int lcur  = (t & 1) << 14;    // current h buffer (byte offset)
    const int lnext = ((t + 1) & 1) << 14;

    // x gather for THIS step (idx already in a register): issued first,
    // consumed at the epilogue ~4000cy later -> HBM latency fully hidden.
    const int idx = idxN;
    float4 xv[4];
#pragma unroll
    for (int nt = 0; nt < 4; ++nt)
      xv[nt] = *(const float4*)&Wb[(size_t)idx * HIDDEN + n0 + nt * 16 + quad * 4];
    if (t + 1 < TSTEPS) idxN = inp[b * TSTEPS + t + 1];

    // stream pipeline: issue 2 chunks ahead, consume/issue ping-pong.
    bf16x8 sA[4], sB[4];
    ISSUE(sA, 32); ISSUE(sB, 36);       // nt2 kc0-3, kc4-7

    f32x4 a0 = {0.f,0.f,0.f,0.f}, a1 = {0.f,0.f,0.f,0.f};
    f32x4 a2 = {0.f,0.f,0.f,0.f}, a3 = {0.f,0.f,0.f,0.f};

    // resident half: 32 MFMAs (n-tiles 0,1) overlap the stream latency.
#pragma unroll
    for (int kc = 0; kc < 16; ++kc) {
      bf16x8 hf = LDSREAD(kc);
      a0 = __builtin_amdgcn_mfma_f32_16x16x32_bf16(wr[kc],      hf, a0, 0, 0, 0);
      a1 = __builtin_amdgcn_mfma_f32_16x16x32_bf16(wr[16 + kc], hf, a1, 0, 0, 0);
    }

    // streamed half: n-tiles 2,3 (8 chunks of 4 frags).
    CONSUME(sA, a2, 0);   ISSUE(sA, 40);
    CONSUME(sB, a2, 4);   ISSUE(sB, 44);
    CONSUME(sA, a2, 8);   ISSUE(sA, 48);
    CONSUME(sB, a2, 12);  ISSUE(sB, 52);
    CONSUME(sA, a3, 0);   ISSUE(sA, 56);
    CONSUME(sB, a3, 4);   ISSUE(sB, 60);
    CONSUME(sA, a3, 8);
    CONSUME(sB, a3, 12);

    // epilogue: D row=n(quad*4+r), col=b(lrow) -- verified v2-v4 layout.
    EPI(a0, 0); EPI(a1, 1); EPI(a2, 2); EPI(a3, 3);

    // intra-CU step barrier: drain LDS ops only (outH stores stay in
    // flight). Single asm block = memory-ordering point + barrier.
    asm volatile("s_waitcnt lgkmcnt(0)\n\ts_barrier" ::: "memory");
  }
#undef LDSREAD
#undef ISSUE
#undef CONSUME
#undef EPI
}

// ---------------------------------------------------------------------------
// logits_gemm: C[32768][4096] fp32 = A[32768][512]bf16 * B[4096][512]bf16^T + bias
// 128x128 tile, BK=64, global_load_lds width 16, 4 waves x (4x4 16x16 tiles).
__global__ __launch_bounds__(256) void logits_gemm(
    const unsigned short* __restrict__ A,     // outH
    const unsigned short* __restrict__ B,     // W_fc bf16
    const float* __restrict__ bias,           // b_fc
    float* __restrict__ C) {
  __shared__ unsigned short lA[128 * 64];
  __shared__ unsigned short lB[128 * 64];

  const int tid  = threadIdx.x;
  const int wave = tid >> 6, lane = tid & 63;
  const int quad = lane >> 4, lrow = lane & 15;
  const int bx = blockIdx.x;
  const int m0 = (bx >> 5) * 128;   // 256 m-tiles
  const int n0 = (bx & 31) * 128;   // 32 n-tiles
  const int wm = wave & 1, wn = wave >> 1;
  const int lr8 = (lane & 7) * 8;   // k offset within staged chunk
  const int lrw = lane >> 3;        // row within 8-row stage group

  f32x4 acc[4][4];
#pragma unroll
  for (int i = 0; i < 4; ++i)
#pragma unroll
    for (int j = 0; j < 4; ++j) acc[i][j] = (f32x4){0.f, 0.f, 0.f, 0.f};

  for (int kk = 0; kk < 8; ++kk) {
    __syncthreads();
    const int kb = kk * 64;
#pragma unroll
    for (int s = 0; s < 4; ++s) {
      int rA = wave * 32 + s * 8;   // 8 rows per instr, 32 rows per wave
      async16(A + (size_t)(m0 + rA + lrw) * HIDDEN + kb + lr8, &lA[rA * 64]);
      async16(B + (size_t)(n0 + rA + lrw) * HIDDEN + kb + lr8, &lB[rA * 64]);
    }
    __syncthreads();
#pragma unroll
    for (int kc = 0; kc < 2; ++kc) {
      bf16x8 af[4], bq[4];
#pragma unroll
      for (int i = 0; i < 4; ++i) {
        af[i] = *(const bf16x8*)&lA[(wm * 64 + i * 16 + lrow) * 64 + kc * 32 + quad * 8];
        bq[i] = *(const bf16x8*)&lB[(wn * 64 + i * 16 + lrow) * 64 + kc * 32 + quad * 8];
      }
#pragma unroll
      for (int i = 0; i < 4; ++i)
#pragma unroll
        for (int j = 0; j < 4; ++j)
          acc[i][j] = __builtin_amdgcn_mfma_f32_16x16x32_bf16(af[i], bq[j], acc[i][j], 0, 0, 0);
    }
  }

#pragma unroll
  for (int i = 0; i < 4; ++i) {
    int row = m0 + wm * 64 + i * 16 + quad * 4;
#pragma unroll
    for (int j = 0; j < 4; ++j) {
      int col = n0 + wn * 64 + j * 16 + lrow;
      float bs = bias[col];
#pragma unroll
      for (int r = 0; r < 4; ++r)
        C[(size_t)(row + r) * VOCAB + col] = acc[i][j][r] + bs;
    }
  }
}

// ---------------------------------------------------------------------------
extern "C" void kernel_launch(void* const* d_in, const int* in_sizes, int n_in,
                              void* d_out, int out_size, void* d_ws, size_t ws_size,
                              hipStream_t stream) {
  const int*   inp    = (const int*)d_in[0];
  const float* hidden = (const float*)d_in[1];
  const float* W_ih   = (const float*)d_in[2];
  const float* W_hh   = (const float*)d_in[3];
  const float* b_ih   = (const float*)d_in[4];
  const float* b_hh   = (const float*)d_in[5];
  const float* W_fc   = (const float*)d_in[6];
  const float* b_fc   = (const float*)d_in[7];

  char* ws = (char*)d_ws;
  float*          Wb   = (float*)ws;                                  // 8 MB
  unsigned short* Wfcb = (unsigned short*)(ws + (8  << 20));          // 4 MB
  unsigned short* outH = (unsigned short*)(ws + (12 << 20));          // 32 MB
  unsigned short* Wf   = (unsigned short*)(ws + (44 << 20));          // 512 KB

  float* logits = (float*)d_out;                                      // [B,T,V]
  float* hlast  = logits + (size_t)BATCH * TSTEPS * VOCAB;            // [1,B,H]

  build_Wb<<<512, 256, 0, stream>>>(W_ih, b_ih, b_hh, Wb);
  conv_wfc<<<2048, 256, 0, stream>>>(W_fc, Wfcb);
  prep_Wf<<<128, 256, 0, stream>>>(W_hh, Wf);
  rnn_scan<<<NSCAN, 512, 0, stream>>>(Wf, Wb, inp, hidden, outH, hlast);
  logits_gemm<<<8192, 256, 0, stream>>>(outH, Wfcb, b_fc, logits);
}

// Round 5
// 2201.214 us; speedup vs baseline: 2.3178x; 1.5598x over previous
//
#include <hip/hip_runtime.h>

#define VOCAB   4096
#define HIDDEN  512
#define BATCH   64
#define TSTEPS  512
#define NSCAN   4        // scan WGs: batch-split, 16 batches each — no comm

typedef short bf16x8 __attribute__((ext_vector_type(8)));   // 8 bf16 = 4 VGPRs
typedef float f32x4  __attribute__((ext_vector_type(4)));

// fp32 -> bf16 round-to-nearest-even (values are finite; no NaN path needed)
__device__ __forceinline__ unsigned short f2bf(float f) {
  unsigned int x = __float_as_uint(f);
  unsigned int r = (x + 0x7fffu + ((x >> 16) & 1u)) >> 16;
  return (unsigned short)r;
}

// tanh via hw exp + rcp: tanh(x) = 1 - 2/(exp(2x)+1). Rel err ~1e-6.
__device__ __forceinline__ float tanh_fast(float x) {
  float e = __expf(2.0f * x);
  return fmaf(-2.0f, __builtin_amdgcn_rcpf(e + 1.0f), 1.0f);
}

// async global->LDS, 16B per lane: LDS dest = uniform base + lane*16,
// global src is per-lane.
__device__ __forceinline__ void async16(const void* g, void* l) {
  __builtin_amdgcn_global_load_lds(
      (const __attribute__((address_space(1))) unsigned int*)g,
      (__attribute__((address_space(3))) unsigned int*)l, 16, 0, 0);
}

// ---------------------------------------------------------------------------
// build_Wb: Wb[v][h] = W_ih[h][v] + b_ih[h] + b_hh[h]   (fp32, 4096x512)
// 64x64 LDS tile transpose. grid 512 (64 v-tiles x 8 h-tiles), block 256.
__global__ void build_Wb(const float* __restrict__ W_ih,
                         const float* __restrict__ b_ih,
                         const float* __restrict__ b_hh,
                         float* __restrict__ Wb) {
  __shared__ float t[64][65];
  int bx = blockIdx.x;
  int vt = bx & 63, ht = bx >> 6;
  int v0 = vt * 64, h0 = ht * 64;
  int tx = threadIdx.x & 15, ty = threadIdx.x >> 4;
#pragma unroll
  for (int a = 0; a < 4; ++a) {
    int h = h0 + ty + 16 * a;
    float4 v = *(const float4*)&W_ih[(size_t)h * VOCAB + v0 + tx * 4];
    t[ty + 16 * a][tx * 4 + 0] = v.x;
    t[ty + 16 * a][tx * 4 + 1] = v.y;
    t[ty + 16 * a][tx * 4 + 2] = v.z;
    t[ty + 16 * a][tx * 4 + 3] = v.w;
  }
  __syncthreads();
#pragma unroll
  for (int a = 0; a < 4; ++a) {
    int v = v0 + ty + 16 * a;
    int hh = h0 + tx * 4;
    float4 o;
    o.x = t[tx * 4 + 0][ty + 16 * a] + b_ih[hh + 0] + b_hh[hh + 0];
    o.y = t[tx * 4 + 1][ty + 16 * a] + b_ih[hh + 1] + b_hh[hh + 1];
    o.z = t[tx * 4 + 2][ty + 16 * a] + b_ih[hh + 2] + b_hh[hh + 2];
    o.w = t[tx * 4 + 3][ty + 16 * a] + b_ih[hh + 3] + b_hh[hh + 3];
    *(float4*)&Wb[(size_t)v * HIDDEN + hh] = o;
  }
}

// ---------------------------------------------------------------------------
// conv_wfc: W_fc fp32 -> bf16. 2097152 elems, 4/thread, grid 2048 x 256 exact.
__global__ void conv_wfc(const float* __restrict__ W, unsigned short* __restrict__ o) {
  int i = (blockIdx.x * 256 + threadIdx.x) * 4;
  float4 v = *(const float4*)&W[i];
  ushort4 u;
  u.x = f2bf(v.x); u.y = f2bf(v.y); u.z = f2bf(v.z); u.w = f2bf(v.w);
  *(ushort4*)&o[i] = u;
}

// ---------------------------------------------------------------------------
// prep_Wf: W_hh fp32 -> bf16 in MFMA-frag-linear layout.
// Wf[frag f = ntg*16+kc][lane][8]: lane (quad,lrow) holds
//   W_hh[n = ntg*16+lrow][k = kc*32 + quad*8 + j], j=0..7.
// A wave's frag load is 64 consecutive 16B chunks (perfectly coalesced).
// 512 frags x 64 lanes = 32768 threads: grid 128 x 256 exact.
__global__ void prep_Wf(const float* __restrict__ Whh, unsigned short* __restrict__ Wf) {
  int i = blockIdx.x * 256 + threadIdx.x;
  int lane = i & 63, fr = i >> 6;
  int kc = fr & 15, ntg = fr >> 4;
  int n = ntg * 16 + (lane & 15);
  int k = kc * 32 + (lane >> 4) * 8;
  const float* src = Whh + (size_t)n * HIDDEN + k;
  float4 f0 = *(const float4*)src;
  float4 f1 = *(const float4*)(src + 4);
  bf16x8 v;
  v[0] = (short)f2bf(f0.x); v[1] = (short)f2bf(f0.y);
  v[2] = (short)f2bf(f0.z); v[3] = (short)f2bf(f0.w);
  v[4] = (short)f2bf(f1.x); v[5] = (short)f2bf(f1.y);
  v[6] = (short)f2bf(f1.z); v[7] = (short)f2bf(f1.w);
  *(bf16x8*)(Wf + (size_t)i * 8) = v;
}

// ---------------------------------------------------------------------------
// rnn_scan v6: batch-split (4 WGs x 512 thr, 16 batches each, zero inter-WG
// comm) with FULL weight residency on-CU:
//  - __launch_bounds__(512, 2): 2 waves/EU -> 256-VGPR cap. v5's silent
//    failure was the default 128-cap demoting wr[] to per-step L2 reloads
//    (VGPR_Count=128 in the counters); this pins it.
//  - wave w owns n-cols [64w,64w+64) = 4 n-tiles. n-tiles 0-2 (48 frags =
//    192 VGPRs) live in registers; n-tile 3 (16 frags, 8KB/wave) is staged
//    ONCE into LDS at kernel start (64KB total, frag-linear -> ds_read_b128
//    conflict-free). Steady-state VMEM = Wb/inp gathers + outH stores only.
//  - h ([16][512] bf16) double-buffered in LDS (32KB), XOR-swizzled rows;
//    h-frag read ONCE per kc and feeds all 4 accumulators (v5 read it 3x).
//  - one intra-CU barrier/step draining LDS only (outH stays in flight).
//  - MFMA scheme (A=W frag, B=h frag, D row=n col=b) verified in v2-v5.
// LDS total: 32KB h + 64KB W = 96KB/CU.
__global__ __launch_bounds__(512, 2) void rnn_scan(
    const unsigned short* __restrict__ Wf,   // [512 frags][64][8] bf16
    const float* __restrict__ Wb,            // [4096][512] fp32 (biases folded)
    const int* __restrict__ inp,             // [64][512]
    const float* __restrict__ hidden,        // [1][64][512] fp32
    unsigned short* __restrict__ outH,       // [32768][512] bf16 (row=b*T+t)
    float* __restrict__ hlast) {             // [64][512] fp32 (d_out tail)
  __shared__ unsigned short hls[2 * 16 * HIDDEN];   // 32KB h dbuf (swizzled)
  __shared__ unsigned short wls[8 * 16 * 512];      // 64KB: [wave][kc][lane*8]
  char* lb = (char*)hls;

  const int tid  = threadIdx.x;
  const int wv   = tid >> 6, lane = tid & 63;
  const int quad = lane >> 4, lrow = lane & 15;
  const int bg   = blockIdx.x * 16;     // WG's batch base
  const int n0   = wv * 64;             // wave's n-slice
  const int b    = bg + lrow;           // this thread's batch (B-frag col)

  // per-wave frag base: local frag j (=nt*16+kc) at wsb + j*512 shorts
  const unsigned short* wsb = Wf + (size_t)wv * 32768 + lane * 8;

  // stage n-tile 3 (frags 48..63) into LDS: per-lane global src, uniform
  // LDS base (HW adds lane*16). Drained by the __syncthreads below.
  {
    const unsigned short* gsrc = wsb + 48 * 512;      // includes lane*8
    unsigned short* ldst = wls + wv * 16 * 512;       // uniform per wave
#pragma unroll
    for (int kc = 0; kc < 16; ++kc)
      async16(gsrc + kc * 512, ldst + kc * 512);
  }

  // resident frags: n-tiles 0,1,2 -> 192 VGPRs
  bf16x8 wr[48];
#pragma unroll
  for (int j = 0; j < 48; ++j) wr[j] = *(const bf16x8*)(wsb + j * 512);

  // h0 -> LDS buf0 (bf16, swizzled). 512 threads x 16 elems.
  {
    int r = tid >> 5;                   // local batch row 0..15
    int c = (tid & 31) * 16;            // element col
    const float* src = hidden + (size_t)(bg + r) * HIDDEN + c;
    float4 f0 = *(const float4*)(src);
    float4 f1 = *(const float4*)(src + 4);
    float4 f2 = *(const float4*)(src + 8);
    float4 f3 = *(const float4*)(src + 12);
    bf16x8 p0, p1;
    p0[0] = (short)f2bf(f0.x); p0[1] = (short)f2bf(f0.y);
    p0[2] = (short)f2bf(f0.z); p0[3] = (short)f2bf(f0.w);
    p0[4] = (short)f2bf(f1.x); p0[5] = (short)f2bf(f1.y);
    p0[6] = (short)f2bf(f1.z); p0[7] = (short)f2bf(f1.w);
    p1[0] = (short)f2bf(f2.x); p1[1] = (short)f2bf(f2.y);
    p1[2] = (short)f2bf(f2.z); p1[3] = (short)f2bf(f2.w);
    p1[4] = (short)f2bf(f3.x); p1[5] = (short)f2bf(f3.y);
    p1[6] = (short)f2bf(f3.z); p1[7] = (short)f2bf(f3.w);
    int base = r * 1024 + c * 2;
    int sw = (r & 7) << 4;
    *(bf16x8*)(lb + (base ^ sw)) = p0;
    *(bf16x8*)(lb + ((base + 16) ^ sw)) = p1;
  }
  __syncthreads();   // drains vmcnt (W-LDS stage) + lgkm (h writes)

  const int rbase = lrow * 1024 + quad * 16;   // h-frag byte base (row,quad)
  const int swz   = (lrow & 7) << 4;           // bank swizzle
  const char* wlb = (const char*)(wls + wv * 16 * 512) + lane * 16;

#define LDSREAD(KC) (*(const bf16x8*)(lb + lcur + ((rbase + (KC) * 64) ^ swz)))
#define EPI(ACC, NT) do { \
    const int n_ = n0 + (NT) * 16 + quad * 4; \
    float e0 = tanh_fast(xv[NT].x + (ACC)[0]); \
    float e1 = tanh_fast(xv[NT].y + (ACC)[1]); \
    float e2 = tanh_fast(xv[NT].z + (ACC)[2]); \
    float e3 = tanh_fast(xv[NT].w + (ACC)[3]); \
    unsigned long long pk = (unsigned long long)f2bf(e0) \
        | ((unsigned long long)f2bf(e1) << 16) \
        | ((unsigned long long)f2bf(e2) << 32) \
        | ((unsigned long long)f2bf(e3) << 48); \
    *(unsigned long long*)(lb + lnext + ((lrow * 1024 + n_ * 2) ^ swz)) = pk; \
    __builtin_nontemporal_store(pk, \
        (unsigned long long*)&outH[(size_t)(b * TSTEPS + t) * HIDDEN + n_]); \
    if (t == TSTEPS - 1) { \
      float4 o_; o_.x = e0; o_.y = e1; o_.z = e2; o_.w = e3; \
      *(float4*)&hlast[(size_t)b * HIDDEN + n_] = o_; \
    } \
  } while (0)

  int idxN = inp[b * TSTEPS];           // x index for t=0 (prefetched)

  for (int t = 0; t < TSTEPS; ++t) {
    const int lcur  = (t & 1) << 14;    // current h buffer (byte offset)
    const int lnext = ((t + 1) & 1) << 14;

    // x gather for THIS step (idx already in a register): issued first,
    // consumed at the epilogue ~2000cy later -> latency fully hidden.
    const int idx = idxN;
    float4 xv[4];
#pragma unroll
    for (int nt = 0; nt < 4; ++nt)
      xv[nt] = *(const float4*)&Wb[(size_t)idx * HIDDEN + n0 + nt * 16 + quad * 4];
    if (t + 1 < TSTEPS) idxN = inp[b * TSTEPS + t + 1];

    f32x4 a0 = {0.f,0.f,0.f,0.f}, a1 = {0.f,0.f,0.f,0.f};
    f32x4 a2 = {0.f,0.f,0.f,0.f}, a3 = {0.f,0.f,0.f,0.f};

    // 64 MFMAs: h frag read once per kc, feeds all 4 n-tiles.
#pragma unroll
    for (int kc = 0; kc < 16; ++kc) {
      bf16x8 hf = LDSREAD(kc);
      bf16x8 wf = *(const bf16x8*)(wlb + kc * 1024);   // n-tile 3 from LDS
      a0 = __builtin_amdgcn_mfma_f32_16x16x32_bf16(wr[kc],      hf, a0, 0, 0, 0);
      a1 = __builtin_amdgcn_mfma_f32_16x16x32_bf16(wr[16 + kc], hf, a1, 0, 0, 0);
      a2 = __builtin_amdgcn_mfma_f32_16x16x32_bf16(wr[32 + kc], hf, a2, 0, 0, 0);
      a3 = __builtin_amdgcn_mfma_f32_16x16x32_bf16(wf,          hf, a3, 0, 0, 0);
    }

    // epilogue: D row=n(quad*4+r), col=b(lrow) -- verified v2-v5 layout.
    EPI(a0, 0); EPI(a1, 1); EPI(a2, 2); EPI(a3, 3);

    // intra-CU step barrier: drain LDS ops only (outH stores stay in flight).
    asm volatile("s_waitcnt lgkmcnt(0)\n\ts_barrier" ::: "memory");
  }
#undef LDSREAD
#undef EPI
}

// ---------------------------------------------------------------------------
// logits_gemm: C[32768][4096] fp32 = A[32768][512]bf16 * B[4096][512]bf16^T + bias
// 128x128 tile, BK=64, global_load_lds width 16, 4 waves x (4x4 16x16 tiles).
__global__ __launch_bounds__(256) void logits_gemm(
    const unsigned short* __restrict__ A,     // outH
    const unsigned short* __restrict__ B,     // W_fc bf16
    const float* __restrict__ bias,           // b_fc
    float* __restrict__ C) {
  __shared__ unsigned short lA[128 * 64];
  __shared__ unsigned short lB[128 * 64];

  const int tid  = threadIdx.x;
  const int wave = tid >> 6, lane = tid & 63;
  const int quad = lane >> 4, lrow = lane & 15;
  const int bx = blockIdx.x;
  const int m0 = (bx >> 5) * 128;   // 256 m-tiles
  const int n0 = (bx & 31) * 128;   // 32 n-tiles
  const int wm = wave & 1, wn = wave >> 1;
  const int lr8 = (lane & 7) * 8;   // k offset within staged chunk
  const int lrw = lane >> 3;        // row within 8-row stage group

  f32x4 acc[4][4];
#pragma unroll
  for (int i = 0; i < 4; ++i)
#pragma unroll
    for (int j = 0; j < 4; ++j) acc[i][j] = (f32x4){0.f, 0.f, 0.f, 0.f};

  for (int kk = 0; kk < 8; ++kk) {
    __syncthreads();
    const int kb = kk * 64;
#pragma unroll
    for (int s = 0; s < 4; ++s) {
      int rA = wave * 32 + s * 8;   // 8 rows per instr, 32 rows per wave
      async16(A + (size_t)(m0 + rA + lrw) * HIDDEN + kb + lr8, &lA[rA * 64]);
      async16(B + (size_t)(n0 + rA + lrw) * HIDDEN + kb + lr8, &lB[rA * 64]);
    }
    __syncthreads();
#pragma unroll
    for (int kc = 0; kc < 2; ++kc) {
      bf16x8 af[4], bq[4];
#pragma unroll
      for (int i = 0; i < 4; ++i) {
        af[i] = *(const bf16x8*)&lA[(wm * 64 + i * 16 + lrow) * 64 + kc * 32 + quad * 8];
        bq[i] = *(const bf16x8*)&lB[(wn * 64 + i * 16 + lrow) * 64 + kc * 32 + quad * 8];
      }
#pragma unroll
      for (int i = 0; i < 4; ++i)
#pragma unroll
        for (int j = 0; j < 4; ++j)
          acc[i][j] = __builtin_amdgcn_mfma_f32_16x16x32_bf16(af[i], bq[j], acc[i][j], 0, 0, 0);
    }
  }

#pragma unroll
  for (int i = 0; i < 4; ++i) {
    int row = m0 + wm * 64 + i * 16 + quad * 4;
#pragma unroll
    for (int j = 0; j < 4; ++j) {
      int col = n0 + wn * 64 + j * 16 + lrow;
      float bs = bias[col];
#pragma unroll
      for (int r = 0; r < 4; ++r)
        C[(size_t)(row + r) * VOCAB + col] = acc[i][j][r] + bs;
    }
  }
}

// ---------------------------------------------------------------------------
extern "C" void kernel_launch(void* const* d_in, const int* in_sizes, int n_in,
                              void* d_out, int out_size, void* d_ws, size_t ws_size,
                              hipStream_t stream) {
  const int*   inp    = (const int*)d_in[0];
  const float* hidden = (const float*)d_in[1];
  const float* W_ih   = (const float*)d_in[2];
  const float* W_hh   = (const float*)d_in[3];
  const float* b_ih   = (const float*)d_in[4];
  const float* b_hh   = (const float*)d_in[5];
  const float* W_fc   = (const float*)d_in[6];
  const float* b_fc   = (const float*)d_in[7];

  char* ws = (char*)d_ws;
  float*          Wb   = (float*)ws;                                  // 8 MB
  unsigned short* Wfcb = (unsigned short*)(ws + (8  << 20));          // 4 MB
  unsigned short* outH = (unsigned short*)(ws + (12 << 20));          // 32 MB
  unsigned short* Wf   = (unsigned short*)(ws + (44 << 20));          // 512 KB

  float* logits = (float*)d_out;                                      // [B,T,V]
  float* hlast  = logits + (size_t)BATCH * TSTEPS * VOCAB;            // [1,B,H]

  build_Wb<<<512, 256, 0, stream>>>(W_ih, b_ih, b_hh, Wb);
  conv_wfc<<<2048, 256, 0, stream>>>(W_fc, Wfcb);
  prep_Wf<<<128, 256, 0, stream>>>(W_hh, Wf);
  rnn_scan<<<NSCAN, 512, 0, stream>>>(Wf, Wb, inp, hidden, outH, hlast);
  logits_gemm<<<8192, 256, 0, stream>>>(outH, Wfcb, b_fc, logits);
}